// Round 18
// baseline (154.705 us; speedup 1.0000x reference)
//
#include <hip/hip_runtime.h>

// ---------------------------------------------------------------------------
// Causal MHA block: QKV proj (bf16 MFMA) -> flash attention -> out proj.
// B=2, S=2048, E=1024, H=16, D=64.
// r18 = r17 with both GEMMs retiled 64x128 -> 64x64 (2x2 wave quad, 32KB LDS
// -> 5 blocks/CU legal; grids (16,64,3) and (16,64)).  attn/converts
// byte-identical to r17.
// ---------------------------------------------------------------------------

#define EMB 1024
#define SEQ 2048
#define NB 2
#define NH 16
#define HD 64

// 0.125 (1/sqrt(64)) * log2(e): QK logits land in exp2 domain
#define QSCALE 0.18033688011112042f

typedef float f32x4 __attribute__((ext_vector_type(4)));
typedef float floatx4 __attribute__((ext_vector_type(4)));
typedef short short8 __attribute__((ext_vector_type(8)));
typedef __bf16 bf16x8 __attribute__((ext_vector_type(8)));
typedef __bf16 bf16x2 __attribute__((ext_vector_type(2)));
typedef unsigned short ushortx4 __attribute__((ext_vector_type(4)));
typedef unsigned int uintx4 __attribute__((ext_vector_type(4)));

// native f32->bf16 (RNE, compiler emits v_cvt_pk_bf16_f32 for pairs)
__device__ __forceinline__ unsigned short bf16u(float f) {
  __bf16 h = (__bf16)f;
  return __builtin_bit_cast(unsigned short, h);
}

__device__ __forceinline__ unsigned pkbf(float lo, float hi) {
  bf16x2 v;
  v[0] = (__bf16)lo;
  v[1] = (__bf16)hi;
  return __builtin_bit_cast(unsigned, v);
}

__device__ __forceinline__ f32x4 mfma16(short8 a, short8 b, f32x4 c) {
  return __builtin_amdgcn_mfma_f32_16x16x32_bf16(
      __builtin_bit_cast(bf16x8, a), __builtin_bit_cast(bf16x8, b), c, 0, 0, 0);
}

// async global -> LDS, 16B per lane; lds dest is wave-uniform base + lane*16
__device__ __forceinline__ void gload16(const void* g, void* lds) {
  __builtin_amdgcn_global_load_lds(
      (const __attribute__((address_space(1))) unsigned int*)g,
      (__attribute__((address_space(3))) unsigned int*)lds, 16, 0, 0);
}

// ---------------------------------------------------------------------------
// Merged converts: z<4 -> fp32 W[k][n] -> bf16 WT[n][k] (32x32 LDS transpose);
// z==4 -> fp32 x -> bf16 (16 elements/thread, float4-coalesced).
// ---------------------------------------------------------------------------
__global__ __launch_bounds__(256) void cvt_all_kernel(
    const float* __restrict__ x, unsigned short* __restrict__ Xb,
    const float* __restrict__ W0, const float* __restrict__ W1,
    const float* __restrict__ W2, const float* __restrict__ W3,
    unsigned short* __restrict__ T0, unsigned short* __restrict__ T1,
    unsigned short* __restrict__ T2, unsigned short* __restrict__ T3) {
  const int z = blockIdx.z;
  const int t = threadIdx.x;
  if (z == 4) {
    // x convert: 1024 virtual blocks of 4096 elements
    const int blin = blockIdx.y * 32 + blockIdx.x;
    const int base = blin * 4096 + t * 4;
    #pragma unroll
    for (int c = 0; c < 4; ++c) {
      const int idx = base + c * 1024;
      floatx4 v = *(const floatx4*)(x + idx);
      ushortx4 o;
      #pragma unroll
      for (int i = 0; i < 4; ++i) o[i] = bf16u(v[i]);
      *(ushortx4*)(Xb + idx) = o;
    }
    return;
  }
  __shared__ unsigned short tile[32][33];
  const float* W = (z == 0) ? W0 : (z == 1) ? W1 : (z == 2) ? W2 : W3;
  unsigned short* WT = (z == 0) ? T0 : (z == 1) ? T1 : (z == 2) ? T2 : T3;
  const int k0 = blockIdx.x * 32, n0 = blockIdx.y * 32;
  const int r = t >> 3, c = (t & 7) * 4;
  floatx4 v = *(const floatx4*)(W + (k0 + r) * EMB + n0 + c);
  #pragma unroll
  for (int i = 0; i < 4; ++i) tile[r][c + i] = bf16u(v[i]);
  __syncthreads();
  ushortx4 o;
  #pragma unroll
  for (int i = 0; i < 4; ++i) o[i] = tile[c + i][r];
  *(ushortx4*)(WT + (n0 + r) * EMB + k0 + c) = o;
}

// 64x64 staging: A 8 chunks + B 8 chunks (1KB = 8 rows x 128B);
// wave w stages A chunks 2w,2w+1 and B chunks 2w,2w+1 (4 gload16/wave).
#define GEMM_STAGE44(Aptr, Bptr, kt_, buf_)                                  \
    do {                                                                     \
      const int kb_ = (kt_) * 64;                                            \
      _Pragma("unroll")                                                      \
      for (int it = 0; it < 2; ++it) {                                       \
        const int chunk = w * 2 + it;                                        \
        const int row = chunk * 8 + (l >> 3), col = (l & 7) * 8;             \
        gload16(Aptr + (m0 + row) * EMB + kb_ + col,                         \
                (char*)&AsB[buf_][0] + chunk * 1024);                        \
        gload16(Bptr + (n0 + row) * EMB + kb_ + col,                         \
                (char*)&BsB[buf_][0] + chunk * 1024);                        \
      }                                                                      \
    } while (0)

// 64x64 k-loop, 2x2 wave quad: per wave 32x32 output (a[2] x b[2]).
#define GEMM_KLOOP22(OP1, OP2)                                               \
    for (int kk = 0; kk < 64; kk += 32) {                                    \
      short8 a[2], b[2];                                                     \
      _Pragma("unroll")                                                      \
      for (int i = 0; i < 2; ++i)                                            \
        a[i] = *(const short8*)(As + (wr * 32 + i * 16 + ln) * 64 + kk + g * 8); \
      _Pragma("unroll")                                                      \
      for (int j = 0; j < 2; ++j)                                            \
        b[j] = *(const short8*)(Bs + (wc * 32 + j * 16 + ln) * 64 + kk + g * 8); \
      _Pragma("unroll")                                                      \
      for (int i = 0; i < 2; ++i)                                            \
        _Pragma("unroll")                                                    \
        for (int j = 0; j < 2; ++j)                                          \
          acc[i][j] = mfma16(OP1, OP2, acc[i][j]);                           \
    }

// ---------------------------------------------------------------------------
// GEMM: C[m][n] = Xb[m][k] * WT[n][k]^T + bias.  64x64 tile, BK=64, 4 waves
// in a 2x2 quad (per-wave 32x32), 2-phase dbuf, counted vmcnt(4).
// z=0 -> Q[b][h][s][d] (pre-scaled by QSCALE), z=1 -> K[b][h][s][d]:
//   operand-swapped MFMA so regs walk d -> packed ushortx4 stores.
// z=2 -> Vt[b][h][d][s]: normal order so regs walk s -> packed stores.
// Grid (16, 64, 3) = 3072 blocks, LDS 32KB -> 5 blocks/CU legal.
// ---------------------------------------------------------------------------
__global__ __launch_bounds__(256) void gemm_qkv_kernel(
    const unsigned short* __restrict__ Xb,
    const unsigned short* __restrict__ W0, const unsigned short* __restrict__ W1,
    const unsigned short* __restrict__ W2,
    const float* __restrict__ b0, const float* __restrict__ b1,
    const float* __restrict__ b2,
    unsigned short* __restrict__ Qo, unsigned short* __restrict__ Ko,
    unsigned short* __restrict__ Vo) {
  __shared__ __align__(16) unsigned short AsB[2][64 * 64];
  __shared__ __align__(16) unsigned short BsB[2][64 * 64];
  const int z = blockIdx.z;
  const unsigned short* Wt = (z == 0) ? W0 : ((z == 1) ? W1 : W2);
  const float* bias = (z == 0) ? b0 : ((z == 1) ? b1 : b2);
  const bool sw = (z != 2);
  const int m0 = blockIdx.y * 64, n0 = blockIdx.x * 64;
  const int tid = threadIdx.x, l = tid & 63, w = tid >> 6;
  const int g = l >> 4, ln = l & 15;
  const int wr = w >> 1, wc = w & 1;

  f32x4 acc[2][2];
  #pragma unroll
  for (int i = 0; i < 2; ++i)
    #pragma unroll
    for (int j = 0; j < 2; ++j) acc[i][j] = (f32x4){0.f, 0.f, 0.f, 0.f};

  GEMM_STAGE44(Xb, Wt, 0, 0);
  #pragma unroll 1
  for (int kt = 0; kt < 16; ++kt) {
    const int cur = kt & 1;
    if (kt + 1 < 16) {
      GEMM_STAGE44(Xb, Wt, kt + 1, cur ^ 1);
      asm volatile("s_waitcnt vmcnt(4)" ::: "memory");
    } else {
      asm volatile("s_waitcnt vmcnt(0)" ::: "memory");
    }
    __builtin_amdgcn_s_barrier();
    const unsigned short* As = &AsB[cur][0];
    const unsigned short* Bs = &BsB[cur][0];
    if (sw) {
      GEMM_KLOOP22(b[j], a[i])
    } else {
      GEMM_KLOOP22(a[i], b[j])
    }
    asm volatile("" ::: "memory");
    __builtin_amdgcn_s_barrier();
  }

  if (sw) {
    // regs walk n (=d): packed stores along d for Q/K [b][h][s][d]
    unsigned short* dst = (z == 0) ? Qo : Ko;
    const float osc = (z == 0) ? QSCALE : 1.0f;
    #pragma unroll
    for (int j = 0; j < 2; ++j) {
      const int n = n0 + wc * 32 + j * 16 + 4 * g;
      floatx4 bv_ = *(const floatx4*)(bias + n);
      const int h = n >> 6, d = n & 63;
      #pragma unroll
      for (int i = 0; i < 2; ++i) {
        const int m = m0 + wr * 32 + i * 16 + ln;   // global s-row
        const int bb = m >> 11, ss = m & 2047;
        ushortx4 o;
        #pragma unroll
        for (int e = 0; e < 4; ++e) o[e] = bf16u((acc[i][j][e] + bv_[e]) * osc);
        *(ushortx4*)(dst + ((bb * NH + h) * SEQ + ss) * HD + d) = o;
      }
    }
  } else {
    // regs walk m (=s): packed stores along s for Vt [b][h][d][s]
    #pragma unroll
    for (int j = 0; j < 2; ++j) {
      const int n = n0 + wc * 32 + j * 16 + ln;
      const float bgain = bias[n];
      const int h = n >> 6, d = n & 63;
      #pragma unroll
      for (int i = 0; i < 2; ++i) {
        const int mf = m0 + wr * 32 + i * 16 + 4 * g;
        const int bb = mf >> 11, ss = mf & 2047;
        ushortx4 o;
        #pragma unroll
        for (int e = 0; e < 4; ++e) o[e] = bf16u(acc[i][j][e] + bgain);
        *(ushortx4*)(Vo + ((bb * NH + h) * HD + d) * SEQ + ss) = o;
      }
    }
  }
}

// ---------------------------------------------------------------------------
// Causal flash attention (r9 known-good: 66.5 us).  Unchanged from r17.
// ---------------------------------------------------------------------------
__global__ __launch_bounds__(512) void attn_kernel(
    const unsigned short* __restrict__ Q, const unsigned short* __restrict__ K,
    const unsigned short* __restrict__ Vt, unsigned short* __restrict__ O) {
  __shared__ __align__(16) unsigned short Kt[2][128 * 64];
  __shared__ __align__(16) unsigned short Vl[2][64 * 128];
  const int id = blockIdx.x;
  const int bh = id & 31;
  const int grp = id >> 5;
  const int T = (grp < 8) ? (15 - grp) : (grp - 8);
  const int h = bh & 15, b = bh >> 4;
  const int tid = threadIdx.x, l = tid & 63, w = tid >> 6;   // w = 0..7
  const int g = l >> 4, ln = l & 15;
  const size_t baseQK = (size_t)bh * SEQ * HD;   // [s][d]
  const size_t baseV = (size_t)bh * HD * SEQ;    // [d][s]
  const int xr = ln & 7;                          // K read-side swizzle xor
  const int srcA = ((g & 1) << 5) + ln;           // P-shuffle source lanes
  const int srcB = srcA + 16;
  const bool hi = (g >> 1) != 0;

  // K staging: chunks 2w,2w+1 of 16 (1KB = 8 rows x 128B)
  const int kr0 = (2 * w) * 8 + (l >> 3), kr1 = (2 * w + 1) * 8 + (l >> 3);
  const int kc0 = (l & 7) ^ (kr0 & 7), kc1 = (l & 7) ^ (kr1 & 7);
  // V staging: chunks 2w,2w+1 of 16 (1KB = 4 rows x 256B)
  const int vr0 = (2 * w) * 4 + (l >> 4), vr1 = (2 * w + 1) * 4 + (l >> 4);
  const int vc0 = (l & 15) ^ (vr0 & 15), vc1 = (l & 15) ^ (vr1 & 15);

  const int nkt = T + 1;
  const int qw = T * 128 + w * 16;

  // stage kt=0 into buf 0 (4 gload_lds per wave)
  gload16(K + baseQK + (size_t)kr0 * HD + kc0 * 8,
          (char*)&Kt[0][0] + (2 * w) * 1024);
  gload16(K + baseQK + (size_t)kr1 * HD + kc1 * 8,
          (char*)&Kt[0][0] + (2 * w + 1) * 1024);
  gload16(Vt + baseV + (size_t)vr0 * SEQ + vc0 * 8,
          (char*)&Vl[0][0] + (2 * w) * 1024);
  gload16(Vt + baseV + (size_t)vr1 * SEQ + vc1 * 8,
          (char*)&Vl[0][0] + (2 * w + 1) * 1024);

  // Q fragments (B-operand: col = q = ln, contraction d)
  const int qrow = qw + ln;
  short8 qf0 = *(const short8*)(Q + baseQK + (size_t)qrow * HD + g * 8);
  short8 qf1 = *(const short8*)(Q + baseQK + (size_t)qrow * HD + 32 + g * 8);

  float m_run = -1e30f, l_run = 0.f;
  f32x4 acc[4];
  #pragma unroll
  for (int dj = 0; dj < 4; ++dj) acc[dj] = (f32x4){0.f, 0.f, 0.f, 0.f};

  #pragma unroll 1
  for (int kt = 0; kt < nkt; ++kt) {
    const int cur = kt & 1;
    const bool has_next = (kt + 1 < nkt);
    if (has_next) {  // prefetch next 128-key tile into other buffer
      const int nxt = cur ^ 1;
      const size_t kof = (size_t)(kt + 1) * 128;
      gload16(K + baseQK + (kof + kr0) * HD + kc0 * 8,
              (char*)&Kt[nxt][0] + (2 * w) * 1024);
      gload16(K + baseQK + (kof + kr1) * HD + kc1 * 8,
              (char*)&Kt[nxt][0] + (2 * w + 1) * 1024);
      gload16(Vt + baseV + (size_t)vr0 * SEQ + kof + vc0 * 8,
              (char*)&Vl[nxt][0] + (2 * w) * 1024);
      gload16(Vt + baseV + (size_t)vr1 * SEQ + kof + vc1 * 8,
              (char*)&Vl[nxt][0] + (2 * w + 1) * 1024);
      asm volatile("s_waitcnt vmcnt(4)" ::: "memory");
    } else {
      asm volatile("s_waitcnt vmcnt(0)" ::: "memory");
    }
    __builtin_amdgcn_s_barrier();

    const bool last = (kt == T);
    const int jmax = last ? w : 7;

    // QK^T swapped: sv[j][e] = S[q=qw+ln][k = kt*128 + j*16 + 4g+e]
    f32x4 sv[8];
    #pragma unroll
    for (int j = 0; j < 8; ++j)
      sv[j] = (f32x4){-1e30f, -1e30f, -1e30f, -1e30f};
    __builtin_amdgcn_s_setprio(1);
    #pragma unroll
    for (int j = 0; j < 8; ++j) {
      if (j <= jmax) {
        f32x4 t = (f32x4){0.f, 0.f, 0.f, 0.f};
        short8 kf0 = *(const short8*)(
            &Kt[cur][(j * 16 + ln) * 64 + ((g ^ xr) * 8)]);
        t = mfma16(kf0, qf0, t);
        short8 kf1 = *(const short8*)(
            &Kt[cur][(j * 16 + ln) * 64 + (((4 + g) ^ xr) * 8)]);
        t = mfma16(kf1, qf1, t);
        if (last && j == w) {               // triangle tile
          #pragma unroll
          for (int e = 0; e < 4; ++e)
            sv[j][e] = (4 * g + e <= ln) ? t[e] : -1e30f;
        } else {
          sv[j] = t;
        }
      }
    }
    __builtin_amdgcn_s_setprio(0);

    // online softmax (exp2 domain), per q-row = per ln; max as tree
    float tj[8];
    #pragma unroll
    for (int j = 0; j < 8; ++j)
      tj[j] = fmaxf(fmaxf(sv[j][0], sv[j][1]), fmaxf(sv[j][2], sv[j][3]));
    float tm = fmaxf(fmaxf(fmaxf(tj[0], tj[1]), fmaxf(tj[2], tj[3])),
                     fmaxf(fmaxf(tj[4], tj[5]), fmaxf(tj[6], tj[7])));
    tm = fmaxf(tm, __shfl_xor(tm, 16));
    tm = fmaxf(tm, __shfl_xor(tm, 32));
    const float nm = fmaxf(m_run, tm);
    const float al = exp2f(m_run - nm);
    m_run = nm;

    // P = exp2(S - nm), packed to bf16 pairs per j
    unsigned pk[8][2];
    float rs = 0.f;
    #pragma unroll
    for (int j = 0; j < 8; ++j) {
      const float p0 = exp2f(sv[j][0] - nm), p1 = exp2f(sv[j][1] - nm);
      const float p2 = exp2f(sv[j][2] - nm), p3 = exp2f(sv[j][3] - nm);
      rs += (p0 + p1) + (p2 + p3);
      pk[j][0] = pkbf(p0, p1);
      pk[j][1] = pkbf(p2, p3);
    }
    rs += __shfl_xor(rs, 16);
    rs += __shfl_xor(rs, 32);
    l_run = l_run * al + rs;
    #pragma unroll
    for (int dj = 0; dj < 4; ++dj) acc[dj] *= al;

    // build PV B-fragments per 32-key slice ks:
    // lane (g,ln) needs P[q=ln][k = ks*32 + 8g..8g+7]
    const int ksmax = (jmax >> 1) + 1;
    short8 pf[4];
    #pragma unroll
    for (int ks = 0; ks < 4; ++ks) {
      if (ks < ksmax) {
        unsigned a0 = __shfl(pk[2 * ks][0], srcA);
        unsigned a1 = __shfl(pk[2 * ks][1], srcA);
        unsigned a2 = __shfl(pk[2 * ks][0], srcB);
        unsigned a3 = __shfl(pk[2 * ks][1], srcB);
        unsigned b0 = __shfl(pk[2 * ks + 1][0], srcA);
        unsigned b1 = __shfl(pk[2 * ks + 1][1], srcA);
        unsigned b2 = __shfl(pk[2 * ks + 1][0], srcB);
        unsigned b3 = __shfl(pk[2 * ks + 1][1], srcB);
        uintx4 u;
        u[0] = hi ? b0 : a0; u[1] = hi ? b1 : a1;
        u[2] = hi ? b2 : a2; u[3] = hi ? b3 : a3;
        pf[ks] = __builtin_bit_cast(short8, u);
      }
    }

    // PV swapped: acc rows = d (4g+e), cols = q (ln).
    // V LDS row = d (64 rows x 128 cols), colgroup swizzle ^= row&15 (=ln)
    __builtin_amdgcn_s_setprio(1);
    #pragma unroll
    for (int dj = 0; dj < 4; ++dj) {
      #pragma unroll
      for (int ks = 0; ks < 4; ++ks) {
        if (ks < ksmax) {
          short8 vb = *(const short8*)(
              &Vl[cur][(dj * 16 + ln) * 128 + (((ks * 4 + g) ^ ln) * 8)]);
          acc[dj] = mfma16(vb, pf[ks], acc[dj]);
        }
      }
    }
    __builtin_amdgcn_s_setprio(0);

    asm volatile("" ::: "memory");
    __builtin_amdgcn_s_barrier();
  }

  // epilogue: O[q = qw+ln][d = dj*16 + 4g+e], thread-local 1/l
  const float inv = 1.f / l_run;
  const size_t orow = ((size_t)b * SEQ + qw + ln) * EMB + h * HD;
  #pragma unroll
  for (int dj = 0; dj < 4; ++dj) {
    ushortx4 o;
    #pragma unroll
    for (int e = 0; e < 4; ++e) o[e] = bf16u(acc[dj][e] * inv);
    *(ushortx4*)(O + orow + dj * 16 + 4 * g) = o;
  }
}

// ---------------------------------------------------------------------------
// Output projection: fp32 out = AttnOut(bf16) @ Wo + bo.  64x64 tile, 2x2
// wave quad, operand-swapped (regs walk n -> float4 stores), vmcnt(4).
// Grid (16, 64) = 1024 blocks.
// ---------------------------------------------------------------------------
__global__ __launch_bounds__(256) void gemm_o_kernel(
    const unsigned short* __restrict__ Ab, const unsigned short* __restrict__ Wt,
    const float* __restrict__ bias, float* __restrict__ out) {
  __shared__ __align__(16) unsigned short AsB[2][64 * 64];
  __shared__ __align__(16) unsigned short BsB[2][64 * 64];
  const int m0 = blockIdx.y * 64, n0 = blockIdx.x * 64;
  const int tid = threadIdx.x, l = tid & 63, w = tid >> 6;
  const int g = l >> 4, ln = l & 15;
  const int wr = w >> 1, wc = w & 1;

  f32x4 acc[2][2];
  #pragma unroll
  for (int i = 0; i < 2; ++i)
    #pragma unroll
    for (int j = 0; j < 2; ++j) acc[i][j] = (f32x4){0.f, 0.f, 0.f, 0.f};

  GEMM_STAGE44(Ab, Wt, 0, 0);
  #pragma unroll 1
  for (int kt = 0; kt < 16; ++kt) {
    const int cur = kt & 1;
    if (kt + 1 < 16) {
      GEMM_STAGE44(Ab, Wt, kt + 1, cur ^ 1);
      asm volatile("s_waitcnt vmcnt(4)" ::: "memory");
    } else {
      asm volatile("s_waitcnt vmcnt(0)" ::: "memory");
    }
    __builtin_amdgcn_s_barrier();
    const unsigned short* As = &AsB[cur][0];
    const unsigned short* Bs = &BsB[cur][0];
    GEMM_KLOOP22(b[j], a[i])
    asm volatile("" ::: "memory");
    __builtin_amdgcn_s_barrier();
  }

  // epilogue: regs walk n; n = n0 + wc*32 + j*16 + 4g, m = m0 + wr*32 + i*16 + ln
  #pragma unroll
  for (int j = 0; j < 2; ++j) {
    const int n = n0 + wc * 32 + j * 16 + 4 * g;
    floatx4 bv_ = *(const floatx4*)(bias + n);
    #pragma unroll
    for (int i = 0; i < 2; ++i) {
      const int m = m0 + wr * 32 + i * 16 + ln;
      floatx4 o = acc[i][j] + bv_;
      *(floatx4*)(out + (size_t)m * EMB + n) = o;
    }
  }
}

// ---------------------------------------------------------------------------
extern "C" void kernel_launch(void* const* d_in, const int* in_sizes, int n_in,
                              void* d_out, int out_size, void* d_ws, size_t ws_size,
                              hipStream_t stream) {
  const float* x  = (const float*)d_in[0];
  const float* Wq = (const float*)d_in[1];
  const float* bq = (const float*)d_in[2];
  const float* Wk = (const float*)d_in[3];
  const float* bk = (const float*)d_in[4];
  const float* Wv = (const float*)d_in[5];
  const float* bv = (const float*)d_in[6];
  const float* Wo = (const float*)d_in[7];
  const float* bo = (const float*)d_in[8];
  float* out = (float*)d_out;

  char* ws = (char*)d_ws;
  unsigned short* Xb  = (unsigned short*)(ws);              // 8 MB  [4096][1024]
  unsigned short* WqT = (unsigned short*)(ws + 8388608);    // 2 MB each [n][k]
  unsigned short* WkT = (unsigned short*)(ws + 10485760);
  unsigned short* WvT = (unsigned short*)(ws + 12582912);
  unsigned short* WoT = (unsigned short*)(ws + 14680064);
  unsigned short* Qb  = (unsigned short*)(ws + 16777216);   // 8 MB [b][h][s][d]
  unsigned short* Kb  = (unsigned short*)(ws + 25165824);   // 8 MB [b][h][s][d]
  unsigned short* Vtb = (unsigned short*)(ws + 33554432);   // 8 MB [b][h][d][s]
  unsigned short* Ao  = Xb;  // attention output reuses Xb (stream-ordered)

  hipLaunchKernelGGL(cvt_all_kernel, dim3(32, 32, 5), dim3(256), 0, stream,
                     x, Xb, Wq, Wk, Wv, Wo, WqT, WkT, WvT, WoT);
  hipLaunchKernelGGL(gemm_qkv_kernel, dim3(16, 64, 3), dim3(256), 0, stream,
                     Xb, WqT, WkT, WvT, bq, bk, bv, Qb, Kb, Vtb);
  hipLaunchKernelGGL(attn_kernel, dim3(512), dim3(512), 0, stream,
                     Qb, Kb, Vtb, Ao);
  hipLaunchKernelGGL(gemm_o_kernel, dim3(16, 64), dim3(256), 0, stream,
                     Ao, WoT, bo, out);
}

// Round 19
// 145.955 us; speedup vs baseline: 1.0599x; 1.0599x over previous
//
#include <hip/hip_runtime.h>

// ---------------------------------------------------------------------------
// Causal MHA block: QKV proj (bf16 MFMA) -> flash attention -> out proj.
// B=2, S=2048, E=1024, H=16, D=64.
// r19 = r17 (measured best, 145.7 us): merged converts + 64x128 2-phase GEMMs
// (3 co-resident blocks/CU) + r9 attention (structural wall at 66.6 us).
// r18's 64x64 retile regressed (intensity loss > co-residency gain) - reverted.
// ---------------------------------------------------------------------------

#define EMB 1024
#define SEQ 2048
#define NB 2
#define NH 16
#define HD 64

// 0.125 (1/sqrt(64)) * log2(e): QK logits land in exp2 domain
#define QSCALE 0.18033688011112042f

typedef float f32x4 __attribute__((ext_vector_type(4)));
typedef float floatx4 __attribute__((ext_vector_type(4)));
typedef short short8 __attribute__((ext_vector_type(8)));
typedef __bf16 bf16x8 __attribute__((ext_vector_type(8)));
typedef __bf16 bf16x2 __attribute__((ext_vector_type(2)));
typedef unsigned short ushortx4 __attribute__((ext_vector_type(4)));
typedef unsigned int uintx4 __attribute__((ext_vector_type(4)));

// native f32->bf16 (RNE, compiler emits v_cvt_pk_bf16_f32 for pairs)
__device__ __forceinline__ unsigned short bf16u(float f) {
  __bf16 h = (__bf16)f;
  return __builtin_bit_cast(unsigned short, h);
}

__device__ __forceinline__ unsigned pkbf(float lo, float hi) {
  bf16x2 v;
  v[0] = (__bf16)lo;
  v[1] = (__bf16)hi;
  return __builtin_bit_cast(unsigned, v);
}

__device__ __forceinline__ f32x4 mfma16(short8 a, short8 b, f32x4 c) {
  return __builtin_amdgcn_mfma_f32_16x16x32_bf16(
      __builtin_bit_cast(bf16x8, a), __builtin_bit_cast(bf16x8, b), c, 0, 0, 0);
}

// async global -> LDS, 16B per lane; lds dest is wave-uniform base + lane*16
__device__ __forceinline__ void gload16(const void* g, void* lds) {
  __builtin_amdgcn_global_load_lds(
      (const __attribute__((address_space(1))) unsigned int*)g,
      (__attribute__((address_space(3))) unsigned int*)lds, 16, 0, 0);
}

// ---------------------------------------------------------------------------
// Merged converts: z<4 -> fp32 W[k][n] -> bf16 WT[n][k] (32x32 LDS transpose);
// z==4 -> fp32 x -> bf16 (16 elements/thread, float4-coalesced).
// ---------------------------------------------------------------------------
__global__ __launch_bounds__(256) void cvt_all_kernel(
    const float* __restrict__ x, unsigned short* __restrict__ Xb,
    const float* __restrict__ W0, const float* __restrict__ W1,
    const float* __restrict__ W2, const float* __restrict__ W3,
    unsigned short* __restrict__ T0, unsigned short* __restrict__ T1,
    unsigned short* __restrict__ T2, unsigned short* __restrict__ T3) {
  const int z = blockIdx.z;
  const int t = threadIdx.x;
  if (z == 4) {
    // x convert: 1024 virtual blocks of 4096 elements
    const int blin = blockIdx.y * 32 + blockIdx.x;
    const int base = blin * 4096 + t * 4;
    #pragma unroll
    for (int c = 0; c < 4; ++c) {
      const int idx = base + c * 1024;
      floatx4 v = *(const floatx4*)(x + idx);
      ushortx4 o;
      #pragma unroll
      for (int i = 0; i < 4; ++i) o[i] = bf16u(v[i]);
      *(ushortx4*)(Xb + idx) = o;
    }
    return;
  }
  __shared__ unsigned short tile[32][33];
  const float* W = (z == 0) ? W0 : (z == 1) ? W1 : (z == 2) ? W2 : W3;
  unsigned short* WT = (z == 0) ? T0 : (z == 1) ? T1 : (z == 2) ? T2 : T3;
  const int k0 = blockIdx.x * 32, n0 = blockIdx.y * 32;
  const int r = t >> 3, c = (t & 7) * 4;
  floatx4 v = *(const floatx4*)(W + (k0 + r) * EMB + n0 + c);
  #pragma unroll
  for (int i = 0; i < 4; ++i) tile[r][c + i] = bf16u(v[i]);
  __syncthreads();
  ushortx4 o;
  #pragma unroll
  for (int i = 0; i < 4; ++i) o[i] = tile[c + i][r];
  *(ushortx4*)(WT + (n0 + r) * EMB + k0 + c) = o;
}

// 64x128 staging: A 8 chunks (wave w: 2w,2w+1), B 16 chunks (wave w: 4w..4w+3)
#define GEMM_STAGE64(Aptr, Bptr, kt_, buf_)                                  \
    do {                                                                     \
      const int kb_ = (kt_) * 64;                                            \
      _Pragma("unroll")                                                      \
      for (int it = 0; it < 2; ++it) {                                       \
        const int chunk = w * 2 + it;                                        \
        const int lin = chunk * 64 + l;                                      \
        const int row = lin >> 3, col = (l & 7) * 8;                         \
        gload16(Aptr + (m0 + row) * EMB + kb_ + col,                         \
                (char*)&AsB[buf_][0] + chunk * 1024);                        \
      }                                                                      \
      _Pragma("unroll")                                                      \
      for (int it = 0; it < 4; ++it) {                                       \
        const int chunk = w * 4 + it;                                        \
        const int lin = chunk * 64 + l;                                      \
        const int row = lin >> 3, col = (l & 7) * 8;                         \
        gload16(Bptr + (n0 + row) * EMB + kb_ + col,                         \
                (char*)&BsB[buf_][0] + chunk * 1024);                        \
      }                                                                      \
    } while (0)

// 64x128 k-loop: a[4] over 64 m-rows, b[2] over wave's 32 n-cols at w*32
#define GEMM_KLOOP64(OP1, OP2)                                               \
    for (int kk = 0; kk < 64; kk += 32) {                                    \
      short8 a[4], b[2];                                                     \
      _Pragma("unroll")                                                      \
      for (int i = 0; i < 4; ++i)                                            \
        a[i] = *(const short8*)(As + (i * 16 + ln) * 64 + kk + g * 8);       \
      _Pragma("unroll")                                                      \
      for (int j = 0; j < 2; ++j)                                            \
        b[j] = *(const short8*)(Bs + (w * 32 + j * 16 + ln) * 64 + kk + g * 8); \
      _Pragma("unroll")                                                      \
      for (int i = 0; i < 4; ++i)                                            \
        _Pragma("unroll")                                                    \
        for (int j = 0; j < 2; ++j)                                          \
          acc[i][j] = mfma16(OP1, OP2, acc[i][j]);                           \
    }

// ---------------------------------------------------------------------------
// GEMM: C[m][n] = Xb[m][k] * WT[n][k]^T + bias.  64x128 tile, BK=64, 4 waves
// (wave index on N: per-wave 64x32 output), 2-phase dbuf, counted vmcnt(6).
// z=0 -> Q[b][h][s][d] (pre-scaled by QSCALE), z=1 -> K[b][h][s][d]:
//   operand-swapped MFMA so regs walk d -> packed ushortx4 stores.
// z=2 -> Vt[b][h][d][s]: normal order so regs walk s -> packed stores.
// Grid (8, 64, 3) = 1536 blocks, LDS 48KB -> 3 co-resident blocks/CU.
// ---------------------------------------------------------------------------
__global__ __launch_bounds__(256) void gemm_qkv_kernel(
    const unsigned short* __restrict__ Xb,
    const unsigned short* __restrict__ W0, const unsigned short* __restrict__ W1,
    const unsigned short* __restrict__ W2,
    const float* __restrict__ b0, const float* __restrict__ b1,
    const float* __restrict__ b2,
    unsigned short* __restrict__ Qo, unsigned short* __restrict__ Ko,
    unsigned short* __restrict__ Vo) {
  __shared__ __align__(16) unsigned short AsB[2][64 * 64];
  __shared__ __align__(16) unsigned short BsB[2][128 * 64];
  const int z = blockIdx.z;
  const unsigned short* Wt = (z == 0) ? W0 : ((z == 1) ? W1 : W2);
  const float* bias = (z == 0) ? b0 : ((z == 1) ? b1 : b2);
  const bool sw = (z != 2);
  const int m0 = blockIdx.y * 64, n0 = blockIdx.x * 128;
  const int tid = threadIdx.x, l = tid & 63, w = tid >> 6;
  const int g = l >> 4, ln = l & 15;

  f32x4 acc[4][2];
  #pragma unroll
  for (int i = 0; i < 4; ++i)
    #pragma unroll
    for (int j = 0; j < 2; ++j) acc[i][j] = (f32x4){0.f, 0.f, 0.f, 0.f};

  GEMM_STAGE64(Xb, Wt, 0, 0);
  #pragma unroll 1
  for (int kt = 0; kt < 16; ++kt) {
    const int cur = kt & 1;
    if (kt + 1 < 16) {
      GEMM_STAGE64(Xb, Wt, kt + 1, cur ^ 1);
      asm volatile("s_waitcnt vmcnt(6)" ::: "memory");
    } else {
      asm volatile("s_waitcnt vmcnt(0)" ::: "memory");
    }
    __builtin_amdgcn_s_barrier();
    const unsigned short* As = &AsB[cur][0];
    const unsigned short* Bs = &BsB[cur][0];
    if (sw) {
      GEMM_KLOOP64(b[j], a[i])
    } else {
      GEMM_KLOOP64(a[i], b[j])
    }
    asm volatile("" ::: "memory");
    __builtin_amdgcn_s_barrier();
  }

  if (sw) {
    // regs walk n (=d): packed stores along d for Q/K [b][h][s][d]
    unsigned short* dst = (z == 0) ? Qo : Ko;
    const float osc = (z == 0) ? QSCALE : 1.0f;
    #pragma unroll
    for (int j = 0; j < 2; ++j) {
      const int n = n0 + w * 32 + j * 16 + 4 * g;
      floatx4 bv_ = *(const floatx4*)(bias + n);
      const int h = n >> 6, d = n & 63;
      #pragma unroll
      for (int i = 0; i < 4; ++i) {
        const int m = m0 + i * 16 + ln;      // global s-row
        const int bb = m >> 11, ss = m & 2047;
        ushortx4 o;
        #pragma unroll
        for (int e = 0; e < 4; ++e) o[e] = bf16u((acc[i][j][e] + bv_[e]) * osc);
        *(ushortx4*)(dst + ((bb * NH + h) * SEQ + ss) * HD + d) = o;
      }
    }
  } else {
    // regs walk m (=s): packed stores along s for Vt [b][h][d][s]
    #pragma unroll
    for (int j = 0; j < 2; ++j) {
      const int n = n0 + w * 32 + j * 16 + ln;
      const float bgain = bias[n];
      const int h = n >> 6, d = n & 63;
      #pragma unroll
      for (int i = 0; i < 4; ++i) {
        const int mf = m0 + i * 16 + 4 * g;
        const int bb = mf >> 11, ss = mf & 2047;
        ushortx4 o;
        #pragma unroll
        for (int e = 0; e < 4; ++e) o[e] = bf16u(acc[i][j][e] + bgain);
        *(ushortx4*)(Vo + ((bb * NH + h) * HD + d) * SEQ + ss) = o;
      }
    }
  }
}

// ---------------------------------------------------------------------------
// Causal flash attention (r9 known-good: 66.5 us).  8 waves, QBLK=128
// (16 q-rows/wave), KVBLK=128 double-buffered (64KB LDS).  Grid 512 1-D:
// bh = id&31 (4 bh per XCD slot), complementary T-pairing:
// grp = id>>5; T = grp<8 ? 15-grp : grp-8  (every CU-pair sums to 17 iters).
// K LDS [128][64] (8-group XOR swizzle); V LDS [64][128] (16-group XOR
// swizzle).  kt<T: 8 full j-fragments; kt==T: jmax=w, triangle at j==w.
// ---------------------------------------------------------------------------
__global__ __launch_bounds__(512) void attn_kernel(
    const unsigned short* __restrict__ Q, const unsigned short* __restrict__ K,
    const unsigned short* __restrict__ Vt, unsigned short* __restrict__ O) {
  __shared__ __align__(16) unsigned short Kt[2][128 * 64];
  __shared__ __align__(16) unsigned short Vl[2][64 * 128];
  const int id = blockIdx.x;
  const int bh = id & 31;
  const int grp = id >> 5;
  const int T = (grp < 8) ? (15 - grp) : (grp - 8);
  const int h = bh & 15, b = bh >> 4;
  const int tid = threadIdx.x, l = tid & 63, w = tid >> 6;   // w = 0..7
  const int g = l >> 4, ln = l & 15;
  const size_t baseQK = (size_t)bh * SEQ * HD;   // [s][d]
  const size_t baseV = (size_t)bh * HD * SEQ;    // [d][s]
  const int xr = ln & 7;                          // K read-side swizzle xor
  const int srcA = ((g & 1) << 5) + ln;           // P-shuffle source lanes
  const int srcB = srcA + 16;
  const bool hi = (g >> 1) != 0;

  // K staging: chunks 2w,2w+1 of 16 (1KB = 8 rows x 128B)
  const int kr0 = (2 * w) * 8 + (l >> 3), kr1 = (2 * w + 1) * 8 + (l >> 3);
  const int kc0 = (l & 7) ^ (kr0 & 7), kc1 = (l & 7) ^ (kr1 & 7);
  // V staging: chunks 2w,2w+1 of 16 (1KB = 4 rows x 256B)
  const int vr0 = (2 * w) * 4 + (l >> 4), vr1 = (2 * w + 1) * 4 + (l >> 4);
  const int vc0 = (l & 15) ^ (vr0 & 15), vc1 = (l & 15) ^ (vr1 & 15);

  const int nkt = T + 1;
  const int qw = T * 128 + w * 16;

  // stage kt=0 into buf 0 (4 gload_lds per wave)
  gload16(K + baseQK + (size_t)kr0 * HD + kc0 * 8,
          (char*)&Kt[0][0] + (2 * w) * 1024);
  gload16(K + baseQK + (size_t)kr1 * HD + kc1 * 8,
          (char*)&Kt[0][0] + (2 * w + 1) * 1024);
  gload16(Vt + baseV + (size_t)vr0 * SEQ + vc0 * 8,
          (char*)&Vl[0][0] + (2 * w) * 1024);
  gload16(Vt + baseV + (size_t)vr1 * SEQ + vc1 * 8,
          (char*)&Vl[0][0] + (2 * w + 1) * 1024);

  // Q fragments (B-operand: col = q = ln, contraction d)
  const int qrow = qw + ln;
  short8 qf0 = *(const short8*)(Q + baseQK + (size_t)qrow * HD + g * 8);
  short8 qf1 = *(const short8*)(Q + baseQK + (size_t)qrow * HD + 32 + g * 8);

  float m_run = -1e30f, l_run = 0.f;
  f32x4 acc[4];
  #pragma unroll
  for (int dj = 0; dj < 4; ++dj) acc[dj] = (f32x4){0.f, 0.f, 0.f, 0.f};

  #pragma unroll 1
  for (int kt = 0; kt < nkt; ++kt) {
    const int cur = kt & 1;
    const bool has_next = (kt + 1 < nkt);
    if (has_next) {  // prefetch next 128-key tile into other buffer
      const int nxt = cur ^ 1;
      const size_t kof = (size_t)(kt + 1) * 128;
      gload16(K + baseQK + (kof + kr0) * HD + kc0 * 8,
              (char*)&Kt[nxt][0] + (2 * w) * 1024);
      gload16(K + baseQK + (kof + kr1) * HD + kc1 * 8,
              (char*)&Kt[nxt][0] + (2 * w + 1) * 1024);
      gload16(Vt + baseV + (size_t)vr0 * SEQ + kof + vc0 * 8,
              (char*)&Vl[nxt][0] + (2 * w) * 1024);
      gload16(Vt + baseV + (size_t)vr1 * SEQ + kof + vc1 * 8,
              (char*)&Vl[nxt][0] + (2 * w + 1) * 1024);
      asm volatile("s_waitcnt vmcnt(4)" ::: "memory");
    } else {
      asm volatile("s_waitcnt vmcnt(0)" ::: "memory");
    }
    __builtin_amdgcn_s_barrier();

    const bool last = (kt == T);
    const int jmax = last ? w : 7;

    // QK^T swapped: sv[j][e] = S[q=qw+ln][k = kt*128 + j*16 + 4g+e]
    f32x4 sv[8];
    #pragma unroll
    for (int j = 0; j < 8; ++j)
      sv[j] = (f32x4){-1e30f, -1e30f, -1e30f, -1e30f};
    __builtin_amdgcn_s_setprio(1);
    #pragma unroll
    for (int j = 0; j < 8; ++j) {
      if (j <= jmax) {
        f32x4 t = (f32x4){0.f, 0.f, 0.f, 0.f};
        short8 kf0 = *(const short8*)(
            &Kt[cur][(j * 16 + ln) * 64 + ((g ^ xr) * 8)]);
        t = mfma16(kf0, qf0, t);
        short8 kf1 = *(const short8*)(
            &Kt[cur][(j * 16 + ln) * 64 + (((4 + g) ^ xr) * 8)]);
        t = mfma16(kf1, qf1, t);
        if (last && j == w) {               // triangle tile
          #pragma unroll
          for (int e = 0; e < 4; ++e)
            sv[j][e] = (4 * g + e <= ln) ? t[e] : -1e30f;
        } else {
          sv[j] = t;
        }
      }
    }
    __builtin_amdgcn_s_setprio(0);

    // online softmax (exp2 domain), per q-row = per ln; max as tree
    float tj[8];
    #pragma unroll
    for (int j = 0; j < 8; ++j)
      tj[j] = fmaxf(fmaxf(sv[j][0], sv[j][1]), fmaxf(sv[j][2], sv[j][3]));
    float tm = fmaxf(fmaxf(fmaxf(tj[0], tj[1]), fmaxf(tj[2], tj[3])),
                     fmaxf(fmaxf(tj[4], tj[5]), fmaxf(tj[6], tj[7])));
    tm = fmaxf(tm, __shfl_xor(tm, 16));
    tm = fmaxf(tm, __shfl_xor(tm, 32));
    const float nm = fmaxf(m_run, tm);
    const float al = exp2f(m_run - nm);
    m_run = nm;

    // P = exp2(S - nm), packed to bf16 pairs per j
    unsigned pk[8][2];
    float rs = 0.f;
    #pragma unroll
    for (int j = 0; j < 8; ++j) {
      const float p0 = exp2f(sv[j][0] - nm), p1 = exp2f(sv[j][1] - nm);
      const float p2 = exp2f(sv[j][2] - nm), p3 = exp2f(sv[j][3] - nm);
      rs += (p0 + p1) + (p2 + p3);
      pk[j][0] = pkbf(p0, p1);
      pk[j][1] = pkbf(p2, p3);
    }
    rs += __shfl_xor(rs, 16);
    rs += __shfl_xor(rs, 32);
    l_run = l_run * al + rs;
    #pragma unroll
    for (int dj = 0; dj < 4; ++dj) acc[dj] *= al;

    // build PV B-fragments per 32-key slice ks:
    // lane (g,ln) needs P[q=ln][k = ks*32 + 8g..8g+7]
    const int ksmax = (jmax >> 1) + 1;
    short8 pf[4];
    #pragma unroll
    for (int ks = 0; ks < 4; ++ks) {
      if (ks < ksmax) {
        unsigned a0 = __shfl(pk[2 * ks][0], srcA);
        unsigned a1 = __shfl(pk[2 * ks][1], srcA);
        unsigned a2 = __shfl(pk[2 * ks][0], srcB);
        unsigned a3 = __shfl(pk[2 * ks][1], srcB);
        unsigned b0 = __shfl(pk[2 * ks + 1][0], srcA);
        unsigned b1 = __shfl(pk[2 * ks + 1][1], srcA);
        unsigned b2 = __shfl(pk[2 * ks + 1][0], srcB);
        unsigned b3 = __shfl(pk[2 * ks + 1][1], srcB);
        uintx4 u;
        u[0] = hi ? b0 : a0; u[1] = hi ? b1 : a1;
        u[2] = hi ? b2 : a2; u[3] = hi ? b3 : a3;
        pf[ks] = __builtin_bit_cast(short8, u);
      }
    }

    // PV swapped: acc rows = d (4g+e), cols = q (ln).
    // V LDS row = d (64 rows x 128 cols), colgroup swizzle ^= row&15 (=ln)
    __builtin_amdgcn_s_setprio(1);
    #pragma unroll
    for (int dj = 0; dj < 4; ++dj) {
      #pragma unroll
      for (int ks = 0; ks < 4; ++ks) {
        if (ks < ksmax) {
          short8 vb = *(const short8*)(
              &Vl[cur][(dj * 16 + ln) * 128 + (((ks * 4 + g) ^ ln) * 8)]);
          acc[dj] = mfma16(vb, pf[ks], acc[dj]);
        }
      }
    }
    __builtin_amdgcn_s_setprio(0);

    asm volatile("" ::: "memory");
    __builtin_amdgcn_s_barrier();
  }

  // epilogue: O[q = qw+ln][d = dj*16 + 4g+e], thread-local 1/l
  const float inv = 1.f / l_run;
  const size_t orow = ((size_t)b * SEQ + qw + ln) * EMB + h * HD;
  #pragma unroll
  for (int dj = 0; dj < 4; ++dj) {
    ushortx4 o;
    #pragma unroll
    for (int e = 0; e < 4; ++e) o[e] = bf16u(acc[dj][e] * inv);
    *(ushortx4*)(O + orow + dj * 16 + 4 * g) = o;
  }
}

// ---------------------------------------------------------------------------
// Output projection: fp32 out = AttnOut(bf16) @ Wo + bo.
// 64x128 tile, wave index on N, 2-phase, vmcnt(6).  Grid (8,64).
// ---------------------------------------------------------------------------
__global__ __launch_bounds__(256) void gemm_o_kernel(
    const unsigned short* __restrict__ Ab, const unsigned short* __restrict__ Wt,
    const float* __restrict__ bias, float* __restrict__ out) {
  __shared__ __align__(16) unsigned short AsB[2][64 * 64];
  __shared__ __align__(16) unsigned short BsB[2][128 * 64];
  const int m0 = blockIdx.y * 64, n0 = blockIdx.x * 128;
  const int tid = threadIdx.x, l = tid & 63, w = tid >> 6;
  const int g = l >> 4, ln = l & 15;

  f32x4 acc[4][2];
  #pragma unroll
  for (int i = 0; i < 4; ++i)
    #pragma unroll
    for (int j = 0; j < 2; ++j) acc[i][j] = (f32x4){0.f, 0.f, 0.f, 0.f};

  GEMM_STAGE64(Ab, Wt, 0, 0);
  #pragma unroll 1
  for (int kt = 0; kt < 16; ++kt) {
    const int cur = kt & 1;
    if (kt + 1 < 16) {
      GEMM_STAGE64(Ab, Wt, kt + 1, cur ^ 1);
      asm volatile("s_waitcnt vmcnt(6)" ::: "memory");
    } else {
      asm volatile("s_waitcnt vmcnt(0)" ::: "memory");
    }
    __builtin_amdgcn_s_barrier();
    const unsigned short* As = &AsB[cur][0];
    const unsigned short* Bs = &BsB[cur][0];
    GEMM_KLOOP64(b[j], a[i])
    asm volatile("" ::: "memory");
    __builtin_amdgcn_s_barrier();
  }

  // epilogue: regs walk n; n = n0 + w*32 + j*16 + 4g, m = m0 + i*16 + ln
  #pragma unroll
  for (int j = 0; j < 2; ++j) {
    const int n = n0 + w * 32 + j * 16 + 4 * g;
    floatx4 bv_ = *(const floatx4*)(bias + n);
    #pragma unroll
    for (int i = 0; i < 4; ++i) {
      const int m = m0 + i * 16 + ln;
      floatx4 o = acc[i][j] + bv_;
      *(floatx4*)(out + (size_t)m * EMB + n) = o;
    }
  }
}

// ---------------------------------------------------------------------------
extern "C" void kernel_launch(void* const* d_in, const int* in_sizes, int n_in,
                              void* d_out, int out_size, void* d_ws, size_t ws_size,
                              hipStream_t stream) {
  const float* x  = (const float*)d_in[0];
  const float* Wq = (const float*)d_in[1];
  const float* bq = (const float*)d_in[2];
  const float* Wk = (const float*)d_in[3];
  const float* bk = (const float*)d_in[4];
  const float* Wv = (const float*)d_in[5];
  const float* bv = (const float*)d_in[6];
  const float* Wo = (const float*)d_in[7];
  const float* bo = (const float*)d_in[8];
  float* out = (float*)d_out;

  char* ws = (char*)d_ws;
  unsigned short* Xb  = (unsigned short*)(ws);              // 8 MB  [4096][1024]
  unsigned short* WqT = (unsigned short*)(ws + 8388608);    // 2 MB each [n][k]
  unsigned short* WkT = (unsigned short*)(ws + 10485760);
  unsigned short* WvT = (unsigned short*)(ws + 12582912);
  unsigned short* WoT = (unsigned short*)(ws + 14680064);
  unsigned short* Qb  = (unsigned short*)(ws + 16777216);   // 8 MB [b][h][s][d]
  unsigned short* Kb  = (unsigned short*)(ws + 25165824);   // 8 MB [b][h][s][d]
  unsigned short* Vtb = (unsigned short*)(ws + 33554432);   // 8 MB [b][h][d][s]
  unsigned short* Ao  = Xb;  // attention output reuses Xb (stream-ordered)

  hipLaunchKernelGGL(cvt_all_kernel, dim3(32, 32, 5), dim3(256), 0, stream,
                     x, Xb, Wq, Wk, Wv, Wo, WqT, WkT, WvT, WoT);
  hipLaunchKernelGGL(gemm_qkv_kernel, dim3(8, 64, 3), dim3(256), 0, stream,
                     Xb, WqT, WkT, WvT, bq, bk, bv, Qb, Kb, Vtb);
  hipLaunchKernelGGL(attn_kernel, dim3(512), dim3(512), 0, stream,
                     Qb, Kb, Vtb, Ao);
  hipLaunchKernelGGL(gemm_o_kernel, dim3(8, 64), dim3(256), 0, stream,
                     Ao, WoT, bo, out);
}